// Round 1
// 1732.501 us; speedup vs baseline: 1.6742x; 1.6742x over previous
//
#include <hip/hip_runtime.h>

typedef unsigned short u16;
typedef __attribute__((ext_vector_type(8))) short short8;
typedef __attribute__((ext_vector_type(4))) float f32x4;

#define L2E   1.44269504088896340736f
#define SCALE 0.08838834764831845f   // 1/sqrt(128)
#define NEGI  -1e30f
#define WN    ((size_t)4096 * 4096)  // one full [4096][4096] tensor, elems
#define TNB   ((size_t)2048 * 4096)  // one per-b tensor, elems

__device__ __forceinline__ float b2f(u16 u) {
  union { float f; unsigned int i; } v; v.i = ((unsigned int)u) << 16; return v.f;
}
__device__ __forceinline__ u16 f2b(float f) {
  union { float f; unsigned int i; } v; v.f = f;
  unsigned int r = v.i + 0x7fffu + ((v.i >> 16) & 1u);   // RNE
  return (u16)(r >> 16);
}
// async global->LDS, 16B per lane; LDS dest must be wave-uniform base + lane*16
__device__ __forceinline__ void gload16(const u16* g, u16* l) {
  __builtin_amdgcn_global_load_lds((const __attribute__((address_space(1))) void*)g,
                                   (__attribute__((address_space(3))) void*)l, 16, 0, 0);
}
// load 8 fp32, round to 8 bf16
__device__ __forceinline__ short8 ld8_f32_to_bf16(const float* p) {
  float4 a = *(const float4*)p;
  float4 b = *(const float4*)(p + 4);
  short8 pk;
  pk[0] = (short)f2b(a.x); pk[1] = (short)f2b(a.y);
  pk[2] = (short)f2b(a.z); pk[3] = (short)f2b(a.w);
  pk[4] = (short)f2b(b.x); pk[5] = (short)f2b(b.y);
  pk[6] = (short)f2b(b.z); pk[7] = (short)f2b(b.w);
  return pk;
}

// ---------------------------------------------------------------------------
// Streaming fp32 -> bf16 convert, 8 elems/thread. Grid must cover n/8 threads.
// ---------------------------------------------------------------------------
__global__ __launch_bounds__(256) void cvt_bf16(const float* __restrict__ src,
                                                u16* __restrict__ dst)
{
  size_t e = ((size_t)blockIdx.x * 256 + threadIdx.x) * 8;
  *(short8*)(dst + e) = ld8_f32_to_bf16(src + e);
}

// ---------------------------------------------------------------------------
// Pure-bf16 NT GEMM (m97 structure): C[m,n] = sum_k A[m,k]*B[n,k].
// M=N=K=4096. Both operands staged via global_load_lds (async, 16B/lane).
// mode 0: C bf16 [4096][4096].
// mode 1: V-transpose w/ batch split: C[b*TNB + col*2048 + (row&2047)] bf16.
// mode 2: C fp32 [4096][4096].
// ---------------------------------------------------------------------------
__global__ __launch_bounds__(256, 2) void gemm_nt(const u16* __restrict__ A,
    const u16* __restrict__ B, void* __restrict__ Cv, int mode)
{
  __shared__ __align__(16) u16 As[128 * 64];
  __shared__ __align__(16) u16 Bs[128 * 64];
  const int tid  = threadIdx.x;
  const int wave = tid >> 6, lane = tid & 63;
  const int quad = lane >> 4, l16 = lane & 15;
  const int bm = blockIdx.y * 128, bn = blockIdx.x * 128;
  const int wm = (wave >> 1) * 64, wn = (wave & 1) * 64;

  f32x4 acc[4][4];
#pragma unroll
  for (int i = 0; i < 4; i++)
#pragma unroll
    for (int j = 0; j < 4; j++) acc[i][j] = (f32x4)0.0f;

  for (int k0 = 0; k0 < 4096; k0 += 64) {
    __syncthreads();
#pragma unroll
    for (int i = 0; i < 4; i++) {
      int c = tid + i * 256;
      int row = c >> 3, cb = (c & 7) << 3;
      gload16(A + (((size_t)(bm + row)) << 12) + k0 + cb, As + c * 8);
      gload16(B + (((size_t)(bn + row)) << 12) + k0 + cb, Bs + c * 8);
    }
    __syncthreads();
#pragma unroll
    for (int ks = 0; ks < 2; ks++) {
      short8 af[4], bf[4];
#pragma unroll
      for (int t = 0; t < 4; t++) {
        af[t] = *(const short8*)(As + (wm + t * 16 + l16) * 64 + ks * 32 + quad * 8);
        bf[t] = *(const short8*)(Bs + (wn + t * 16 + l16) * 64 + ks * 32 + quad * 8);
      }
#pragma unroll
      for (int mt = 0; mt < 4; mt++)
#pragma unroll
        for (int nt = 0; nt < 4; nt++)
          acc[mt][nt] = __builtin_amdgcn_mfma_f32_16x16x32_bf16(af[mt], bf[nt], acc[mt][nt], 0, 0, 0);
    }
  }
  // epilogue: C/D layout col=lane&15, row=quad*4+reg
#pragma unroll
  for (int mt = 0; mt < 4; mt++)
#pragma unroll
    for (int nt = 0; nt < 4; nt++)
#pragma unroll
      for (int r = 0; r < 4; r++) {
        int row = bm + wm + mt * 16 + quad * 4 + r;
        int col = bn + wn + nt * 16 + l16;
        float v = acc[mt][nt][r];
        if (mode == 2) {
          ((float*)Cv)[(((size_t)row) << 12) + col] = v;
        } else if (mode == 1) {
          ((u16*)Cv)[((size_t)(row >> 11)) * TNB + (((size_t)col) << 11) + (row & 2047)] = f2b(v);
        } else {
          ((u16*)Cv)[(((size_t)row) << 12) + col] = f2b(v);
        }
      }
}

// ---------------------------------------------------------------------------
// RoPE in-place on full-batch Q and K (4096 rows x 4096, bf16). s = row&2047.
// One thread = 4 pairs. fc/fs are fp32 [2048][64].
// ---------------------------------------------------------------------------
__global__ __launch_bounds__(256) void rope_kernel(u16* __restrict__ Q, u16* __restrict__ K,
    const float* __restrict__ fc, const float* __restrict__ fs)
{
  int gid = blockIdx.x * 256 + threadIdx.x;     // 2 tensors * 4096 rows * 512 groups
  int tsel = gid >> 21;
  int r = gid & 2097151;
  int row = r >> 9, gp = r & 511;
  int s = row & 2047;
  int e0 = gp * 8;                 // element offset in row (4 pairs, same head)
  int i0 = (e0 >> 1) & 63;         // pair index within head (multiple of 4)
  u16* p = (tsel ? K : Q) + (((size_t)row) << 12) + e0;
  short8 v = *(const short8*)p;
  float4 c4 = *(const float4*)(fc + s * 64 + i0);
  float4 s4 = *(const float4*)(fs + s * 64 + i0);
  float cc[4] = {c4.x, c4.y, c4.z, c4.w};
  float ss[4] = {s4.x, s4.y, s4.z, s4.w};
  short8 w;
#pragma unroll
  for (int j = 0; j < 4; j++) {
    float a  = b2f((u16)v[2 * j]);
    float bb = b2f((u16)v[2 * j + 1]);
    w[2 * j]     = (short)f2b(a * cc[j] - bb * ss[j]);
    w[2 * j + 1] = (short)f2b(a * ss[j] + bb * cc[j]);
  }
  *(short8*)p = w;
}

// ---------------------------------------------------------------------------
// Adapter K/V projection: a_k[l,e] = sum_d adapter[l,d]*wk[e,d] (same for v).
// fp32 inputs, bf16 outputs. One wave per output element, shuffle-reduce.
// ---------------------------------------------------------------------------
__global__ __launch_bounds__(256) void adapter_kv(const float* __restrict__ adapter,
    const float* __restrict__ wk, const float* __restrict__ wv,
    u16* __restrict__ ak, u16* __restrict__ av)
{
  int gid  = blockIdx.x * 4 + (threadIdx.x >> 6);   // 0..81919
  int lane = threadIdx.x & 63;
  int which = (gid >= 40960) ? 1 : 0;
  int rem = gid - which * 40960;
  int l = rem >> 12, col = rem & 4095;
  const float* w = which ? wv : wk;
  u16* o = which ? av : ak;
  const float* arow = adapter + l * 4096;
  const float* wrow = w + (((size_t)col) << 12);
  float sum = 0.f;
#pragma unroll
  for (int i = 0; i < 8; i++) {
    int e = i * 512 + lane * 8;
    float4 a0 = *(const float4*)(arow + e);
    float4 a1 = *(const float4*)(arow + e + 4);
    float4 w0 = *(const float4*)(wrow + e);
    float4 w1 = *(const float4*)(wrow + e + 4);
    sum += a0.x * w0.x + a0.y * w0.y + a0.z * w0.z + a0.w * w0.w
         + a1.x * w1.x + a1.y * w1.y + a1.z * w1.z + a1.w * w1.w;
  }
#pragma unroll
  for (int off = 1; off < 64; off <<= 1) sum += __shfl_xor(sum, off, 64);
  if (lane == 0) o[rem] = f2b(sum);
}

// ---------------------------------------------------------------------------
// Causal flash attention; blockIdx.z = batch. Block = one h x 128 q-rows.
// Q in A-frags, K/Vt via global_load_lds, KV=64. Vt is [h*128+d, s] per-b.
// ---------------------------------------------------------------------------
__global__ __launch_bounds__(256, 2) void flash_attn(const u16* __restrict__ Q,
    const u16* __restrict__ K, const u16* __restrict__ V, u16* __restrict__ O)
{
  Q += (size_t)blockIdx.z * TNB;
  K += (size_t)blockIdx.z * TNB;
  V += (size_t)blockIdx.z * TNB;
  O += (size_t)blockIdx.z * TNB;
  __shared__ __align__(16) u16 sm[24576];        // 48KB
  u16* Ks = sm;                                  // [64 key][128 d]
  u16* Vs = sm + 8192;                           // [128 d][64 key]
  u16* Ps = sm + 16384;                          // per-wave [32 q][64 key]
  const int tid  = threadIdx.x;
  const int wave = tid >> 6, lane = tid & 63;
  const int quad = lane >> 4, l16 = lane & 15;
  const int qt = blockIdx.x;
  const int h  = blockIdx.y;
  const int q0 = qt * 128;
  const size_t qkBase = (size_t)h * 128;
  const size_t vBase  = ((size_t)(h * 128)) << 11;

  // stage Q tile 128x128 into sm[0..16384)
#pragma unroll
  for (int i = 0; i < 8; i++) {
    int c = tid + i * 256;
    int row = c >> 4, cb = (c & 15) << 3;
    gload16(Q + qkBase + (((size_t)(q0 + row)) << 12) + cb, sm + c * 8);
  }
  __syncthreads();
  short8 qa[2][4];                               // A-frags: 2 m-tiles x 4 d-steps
#pragma unroll
  for (int mt = 0; mt < 2; mt++)
#pragma unroll
    for (int ks = 0; ks < 4; ks++)
      qa[mt][ks] = *(const short8*)(sm + (wave * 32 + mt * 16 + l16) * 128 + ks * 32 + quad * 8);

  f32x4 acc_o[2][8];
#pragma unroll
  for (int mt = 0; mt < 2; mt++)
#pragma unroll
    for (int n = 0; n < 8; n++) acc_o[mt][n] = (f32x4)0.0f;
  float m_st[2][4], l_st[2][4];
#pragma unroll
  for (int mt = 0; mt < 2; mt++)
#pragma unroll
    for (int r = 0; r < 4; r++) { m_st[mt][r] = NEGI; l_st[mt][r] = 0.f; }

  const int qw0 = q0 + wave * 32;
  const int ntiles = 2 * (qt + 1);
  for (int t = 0; t < ntiles; t++) {
    const int kv0 = t * 64;
    __syncthreads();                             // prev tile LDS reads done
#pragma unroll
    for (int i = 0; i < 4; i++) {
      int c = tid + i * 256;
      int krow = c >> 4, kcb = (c & 15) << 3;
      gload16(K + qkBase + (((size_t)(kv0 + krow)) << 12) + kcb, Ks + c * 8);
      int vrow = c >> 3, vcb = (c & 7) << 3;
      gload16(V + vBase + (((size_t)vrow) << 11) + kv0 + vcb, Vs + c * 8);
    }
    __syncthreads();                             // staging visible

    if (kv0 <= qw0 + 31) {                       // wave-uniform causal skip
      f32x4 sc[2][4];
#pragma unroll
      for (int mt = 0; mt < 2; mt++)
#pragma unroll
        for (int nt = 0; nt < 4; nt++) sc[mt][nt] = (f32x4)0.0f;
#pragma unroll
      for (int ks = 0; ks < 4; ks++) {
        short8 kb[4];
#pragma unroll
        for (int nt = 0; nt < 4; nt++)
          kb[nt] = *(const short8*)(Ks + (nt * 16 + l16) * 128 + ks * 32 + quad * 8);
#pragma unroll
        for (int mt = 0; mt < 2; mt++)
#pragma unroll
          for (int nt = 0; nt < 4; nt++)
            sc[mt][nt] = __builtin_amdgcn_mfma_f32_16x16x32_bf16(qa[mt][ks], kb[nt], sc[mt][nt], 0, 0, 0);
      }
      // scale + causal mask
#pragma unroll
      for (int mt = 0; mt < 2; mt++)
#pragma unroll
        for (int nt = 0; nt < 4; nt++)
#pragma unroll
          for (int r = 0; r < 4; r++) {
            int qrow = qw0 + mt * 16 + quad * 4 + r;
            int key  = kv0 + nt * 16 + l16;
            float s = sc[mt][nt][r] * SCALE;
            sc[mt][nt][r] = (key > qrow) ? NEGI : s;
          }
      // online softmax (row = quad*4+r; 16 lanes of the quad share a row)
      float alpha[2][4];
#pragma unroll
      for (int mt = 0; mt < 2; mt++)
#pragma unroll
        for (int r = 0; r < 4; r++) {
          float mx = fmaxf(fmaxf(sc[mt][0][r], sc[mt][1][r]), fmaxf(sc[mt][2][r], sc[mt][3][r]));
          mx = fmaxf(mx, __shfl_xor(mx, 1, 64));
          mx = fmaxf(mx, __shfl_xor(mx, 2, 64));
          mx = fmaxf(mx, __shfl_xor(mx, 4, 64));
          mx = fmaxf(mx, __shfl_xor(mx, 8, 64));
          float mnew = fmaxf(m_st[mt][r], mx);
          float al = __builtin_amdgcn_exp2f((m_st[mt][r] - mnew) * L2E);
          float rs = 0.f;
#pragma unroll
          for (int nt = 0; nt < 4; nt++) {
            float p = __builtin_amdgcn_exp2f((sc[mt][nt][r] - mnew) * L2E);
            sc[mt][nt][r] = p;
            rs += p;
          }
          rs += __shfl_xor(rs, 1, 64);
          rs += __shfl_xor(rs, 2, 64);
          rs += __shfl_xor(rs, 4, 64);
          rs += __shfl_xor(rs, 8, 64);
          l_st[mt][r] = l_st[mt][r] * al + rs;
          m_st[mt][r] = mnew;
          alpha[mt][r] = al;
        }
#pragma unroll
      for (int mt = 0; mt < 2; mt++)
#pragma unroll
        for (int n = 0; n < 8; n++)
#pragma unroll
          for (int r = 0; r < 4; r++) acc_o[mt][n][r] *= alpha[mt][r];
      // P: C-layout -> A-layout via per-wave LDS
      u16* Pw = Ps + wave * 2048;
#pragma unroll
      for (int mt = 0; mt < 2; mt++)
#pragma unroll
        for (int nt = 0; nt < 4; nt++)
#pragma unroll
          for (int r = 0; r < 4; r++)
            Pw[(mt * 16 + quad * 4 + r) * 64 + nt * 16 + l16] = f2b(sc[mt][nt][r]);
      // PV
#pragma unroll
      for (int ks2 = 0; ks2 < 2; ks2++) {
        short8 pa[2];
#pragma unroll
        for (int mt = 0; mt < 2; mt++)
          pa[mt] = *(const short8*)(Pw + (mt * 16 + l16) * 64 + ks2 * 32 + quad * 8);
#pragma unroll
        for (int n = 0; n < 8; n++) {
          short8 vb = *(const short8*)(Vs + (n * 16 + l16) * 64 + ks2 * 32 + quad * 8);
#pragma unroll
          for (int mt = 0; mt < 2; mt++)
            acc_o[mt][n] = __builtin_amdgcn_mfma_f32_16x16x32_bf16(pa[mt], vb, acc_o[mt][n], 0, 0, 0);
        }
      }
    }
  }
  // epilogue: O[q, h*128+d] = acc / l  (bf16)
#pragma unroll
  for (int mt = 0; mt < 2; mt++)
#pragma unroll
    for (int r = 0; r < 4; r++) {
      float inv = 1.0f / l_st[mt][r];
      int qrow = qw0 + mt * 16 + quad * 4 + r;
#pragma unroll
      for (int n = 0; n < 8; n++) {
        int d = n * 16 + l16;
        O[qkBase + (((size_t)qrow) << 12) + d] = f2b(acc_o[mt][n][r] * inv);
      }
    }
}

// ---------------------------------------------------------------------------
// Adapter attention (full batch): AO += tanh(gate[h]) * softmax(q.a_k/sqrt(d)) a_v
// One wave per (row,h); lane owns 2 of the 128 d-dims. row = 0..4095.
// ---------------------------------------------------------------------------
__global__ __launch_bounds__(256) void adapter_attn(const u16* __restrict__ Q,
    const u16* __restrict__ ak, const u16* __restrict__ av,
    const float* __restrict__ gate, u16* __restrict__ AO)
{
  int gid  = blockIdx.x * 4 + (threadIdx.x >> 6);   // 0..131071 = row*32+h
  int lane = threadIdx.x & 63;
  int row = gid >> 5, h = gid & 31;
  float g = tanhf(gate[h]);
  const u16* qp = Q + (((size_t)row) << 12) + h * 128 + lane * 2;
  float qa = b2f(qp[0]), qb = b2f(qp[1]);
  float p[10];
#pragma unroll
  for (int l = 0; l < 10; l++) {
    const u16* kp = ak + l * 4096 + h * 128 + lane * 2;
    p[l] = qa * b2f(kp[0]) + qb * b2f(kp[1]);
  }
#pragma unroll
  for (int l = 0; l < 10; l++)
#pragma unroll
    for (int off = 1; off < 64; off <<= 1) p[l] += __shfl_xor(p[l], off, 64);
  float m = NEGI;
#pragma unroll
  for (int l = 0; l < 10; l++) { p[l] *= SCALE; m = fmaxf(m, p[l]); }
  float sum = 0.f;
#pragma unroll
  for (int l = 0; l < 10; l++) { p[l] = __builtin_amdgcn_exp2f((p[l] - m) * L2E); sum += p[l]; }
  float gi = g / sum;
  float a0 = 0.f, a1 = 0.f;
#pragma unroll
  for (int l = 0; l < 10; l++) {
    const u16* vp = av + l * 4096 + h * 128 + lane * 2;
    a0 += p[l] * b2f(vp[0]);
    a1 += p[l] * b2f(vp[1]);
  }
  u16* op = AO + (((size_t)row) << 12) + h * 128 + lane * 2;
  op[0] = f2b(b2f(op[0]) + gi * a0);
  op[1] = f2b(b2f(op[1]) + gi * a1);
}

// ---------------------------------------------------------------------------
extern "C" void kernel_launch(void* const* d_in, const int* in_sizes, int n_in,
                              void* d_out, int out_size, void* d_ws, size_t ws_size,
                              hipStream_t stream) {
  (void)in_sizes; (void)n_in; (void)out_size; (void)ws_size;
  const float* x       = (const float*)d_in[0];
  const float* wq      = (const float*)d_in[1];
  const float* wk      = (const float*)d_in[2];
  const float* wv      = (const float*)d_in[3];
  const float* wo      = (const float*)d_in[4];
  const float* gate    = (const float*)d_in[5];
  const float* adapter = (const float*)d_in[6];
  const float* fc      = (const float*)d_in[7];
  const float* fs      = (const float*)d_in[8];
  // d_in[9]=mask (implemented as causal), d_in[10]=start_pos (=0)
  float* out = (float*)d_out;

  // ws layout (bf16): wb(32MB) | xb(32MB, aliased by AOf) | Qf | Kf | Vtf | ak | av
  // total ~160.2 MB
  u16* wb  = (u16*)d_ws;         // current weight, converted bf16 [4096][4096]
  u16* xb  = wb + WN;            // x bf16 [4096][4096] (both batches)
  u16* Qf  = xb + WN;            // [4096][4096]
  u16* Kf  = Qf + WN;
  u16* Vtf = Kf + WN;            // per-b [4096 cols][2048 s], 2 batches
  u16* AOf = xb;                 // alias: x dead after V GEMM
  u16* ak  = Vtf + WN;           // [10][4096]
  u16* av  = ak + 40960;

  adapter_kv<<<20480, 256, 0, stream>>>(adapter, wk, wv, ak, av);
  cvt_bf16<<<8192, 256, 0, stream>>>(x, xb);

  cvt_bf16<<<8192, 256, 0, stream>>>(wq, wb);
  gemm_nt<<<dim3(32, 32), 256, 0, stream>>>(xb, wb, Qf, 0);
  cvt_bf16<<<8192, 256, 0, stream>>>(wk, wb);
  gemm_nt<<<dim3(32, 32), 256, 0, stream>>>(xb, wb, Kf, 0);
  cvt_bf16<<<8192, 256, 0, stream>>>(wv, wb);
  gemm_nt<<<dim3(32, 32), 256, 0, stream>>>(xb, wb, Vtf, 1);

  rope_kernel<<<16384, 256, 0, stream>>>(Qf, Kf, fc, fs);
  flash_attn<<<dim3(16, 32, 2), 256, 0, stream>>>(Qf, Kf, Vtf, AOf);
  adapter_attn<<<32768, 256, 0, stream>>>(Qf, ak, av, gate, AOf);

  cvt_bf16<<<8192, 256, 0, stream>>>(wo, wb);
  gemm_nt<<<dim3(32, 32), 256, 0, stream>>>(AOf, wb, out, 2);
}

// Round 2
// 1611.965 us; speedup vs baseline: 1.7994x; 1.0748x over previous
//
#include <hip/hip_runtime.h>

typedef unsigned short u16;
typedef __attribute__((ext_vector_type(8))) short short8;
typedef __attribute__((ext_vector_type(4))) float f32x4;

#define L2E   1.44269504088896340736f
#define SCALE 0.08838834764831845f   // 1/sqrt(128)
#define NEGI  -1e30f
#define WN    ((size_t)4096 * 4096)  // one full [4096][4096] tensor, elems
#define TNB   ((size_t)2048 * 4096)  // one per-b tensor, elems

__device__ __forceinline__ float b2f(u16 u) {
  union { float f; unsigned int i; } v; v.i = ((unsigned int)u) << 16; return v.f;
}
__device__ __forceinline__ u16 f2b(float f) {
  union { float f; unsigned int i; } v; v.f = f;
  unsigned int r = v.i + 0x7fffu + ((v.i >> 16) & 1u);   // RNE
  return (u16)(r >> 16);
}
// async global->LDS, 16B per lane; LDS dest must be wave-uniform base + lane*16
__device__ __forceinline__ void gload16(const u16* g, u16* l) {
  __builtin_amdgcn_global_load_lds((const __attribute__((address_space(1))) void*)g,
                                   (__attribute__((address_space(3))) void*)l, 16, 0, 0);
}
// load 8 fp32, round to 8 bf16
__device__ __forceinline__ short8 ld8_f32_to_bf16(const float* p) {
  float4 a = *(const float4*)p;
  float4 b = *(const float4*)(p + 4);
  short8 pk;
  pk[0] = (short)f2b(a.x); pk[1] = (short)f2b(a.y);
  pk[2] = (short)f2b(a.z); pk[3] = (short)f2b(a.w);
  pk[4] = (short)f2b(b.x); pk[5] = (short)f2b(b.y);
  pk[6] = (short)f2b(b.z); pk[7] = (short)f2b(b.w);
  return pk;
}

// ---------------------------------------------------------------------------
// Streaming fp32 -> bf16 convert, 8 elems/thread.
// ---------------------------------------------------------------------------
__global__ __launch_bounds__(256) void cvt_bf16(const float* __restrict__ src,
                                                u16* __restrict__ dst)
{
  size_t e = ((size_t)blockIdx.x * 256 + threadIdx.x) * 8;
  *(short8*)(dst + e) = ld8_f32_to_bf16(src + e);
}

// ---------------------------------------------------------------------------
// Pure-bf16 NT GEMM (m97 structure): C[m,n] = sum_k A[m,k]*B[n,k].
// M=N=K=4096, both operands via global_load_lds.
// mode 0: C bf16 [4096][4096].
// mode 1: batch-split transpose store: C[(col>>11)*TNB + row*2048 + (col&2047)]
//         (used with A=weight rows=e, B=x rows=s -> coalesced Vt writes).
// mode 2: C fp32 [4096][4096].
// ---------------------------------------------------------------------------
__global__ __launch_bounds__(256, 2) void gemm_nt(const u16* __restrict__ A,
    const u16* __restrict__ B, void* __restrict__ Cv, int mode)
{
  __shared__ __align__(16) u16 As[128 * 64];
  __shared__ __align__(16) u16 Bs[128 * 64];
  const int tid  = threadIdx.x;
  const int wave = tid >> 6, lane = tid & 63;
  const int quad = lane >> 4, l16 = lane & 15;
  const int bm = blockIdx.y * 128, bn = blockIdx.x * 128;
  const int wm = (wave >> 1) * 64, wn = (wave & 1) * 64;

  f32x4 acc[4][4];
#pragma unroll
  for (int i = 0; i < 4; i++)
#pragma unroll
    for (int j = 0; j < 4; j++) acc[i][j] = (f32x4)0.0f;

  for (int k0 = 0; k0 < 4096; k0 += 64) {
    __syncthreads();
#pragma unroll
    for (int i = 0; i < 4; i++) {
      int c = tid + i * 256;
      int row = c >> 3, cb = (c & 7) << 3;
      gload16(A + (((size_t)(bm + row)) << 12) + k0 + cb, As + c * 8);
      gload16(B + (((size_t)(bn + row)) << 12) + k0 + cb, Bs + c * 8);
    }
    __syncthreads();
#pragma unroll
    for (int ks = 0; ks < 2; ks++) {
      short8 af[4], bf[4];
#pragma unroll
      for (int t = 0; t < 4; t++) {
        af[t] = *(const short8*)(As + (wm + t * 16 + l16) * 64 + ks * 32 + quad * 8);
        bf[t] = *(const short8*)(Bs + (wn + t * 16 + l16) * 64 + ks * 32 + quad * 8);
      }
#pragma unroll
      for (int mt = 0; mt < 4; mt++)
#pragma unroll
        for (int nt = 0; nt < 4; nt++)
          acc[mt][nt] = __builtin_amdgcn_mfma_f32_16x16x32_bf16(af[mt], bf[nt], acc[mt][nt], 0, 0, 0);
    }
  }
  // epilogue: C/D layout col=lane&15, row=quad*4+reg
#pragma unroll
  for (int mt = 0; mt < 4; mt++)
#pragma unroll
    for (int nt = 0; nt < 4; nt++)
#pragma unroll
      for (int r = 0; r < 4; r++) {
        int row = bm + wm + mt * 16 + quad * 4 + r;
        int col = bn + wn + nt * 16 + l16;
        float v = acc[mt][nt][r];
        if (mode == 2) {
          ((float*)Cv)[(((size_t)row) << 12) + col] = v;
        } else if (mode == 1) {
          ((u16*)Cv)[((size_t)(col >> 11)) * TNB + (((size_t)row) << 11) + (col & 2047)] = f2b(v);
        } else {
          ((u16*)Cv)[(((size_t)row) << 12) + col] = f2b(v);
        }
      }
}

// ---------------------------------------------------------------------------
// RoPE in-place on full-batch Q and K (4096 rows x 4096, bf16). s = row&2047.
// ---------------------------------------------------------------------------
__global__ __launch_bounds__(256) void rope_kernel(u16* __restrict__ Q, u16* __restrict__ K,
    const float* __restrict__ fc, const float* __restrict__ fs)
{
  int gid = blockIdx.x * 256 + threadIdx.x;     // 2 tensors * 4096 rows * 512 groups
  int tsel = gid >> 21;
  int r = gid & 2097151;
  int row = r >> 9, gp = r & 511;
  int s = row & 2047;
  int e0 = gp * 8;
  int i0 = (e0 >> 1) & 63;
  u16* p = (tsel ? K : Q) + (((size_t)row) << 12) + e0;
  short8 v = *(const short8*)p;
  float4 c4 = *(const float4*)(fc + s * 64 + i0);
  float4 s4 = *(const float4*)(fs + s * 64 + i0);
  float cc[4] = {c4.x, c4.y, c4.z, c4.w};
  float ss[4] = {s4.x, s4.y, s4.z, s4.w};
  short8 w;
#pragma unroll
  for (int j = 0; j < 4; j++) {
    float a  = b2f((u16)v[2 * j]);
    float bb = b2f((u16)v[2 * j + 1]);
    w[2 * j]     = (short)f2b(a * cc[j] - bb * ss[j]);
    w[2 * j + 1] = (short)f2b(a * ss[j] + bb * cc[j]);
  }
  *(short8*)p = w;
}

// ---------------------------------------------------------------------------
// Adapter K/V projection: one wave per output element, shuffle-reduce.
// ---------------------------------------------------------------------------
__global__ __launch_bounds__(256) void adapter_kv(const float* __restrict__ adapter,
    const float* __restrict__ wk, const float* __restrict__ wv,
    u16* __restrict__ ak, u16* __restrict__ av)
{
  int gid  = blockIdx.x * 4 + (threadIdx.x >> 6);   // 0..81919
  int lane = threadIdx.x & 63;
  int which = (gid >= 40960) ? 1 : 0;
  int rem = gid - which * 40960;
  int l = rem >> 12, col = rem & 4095;
  const float* w = which ? wv : wk;
  u16* o = which ? av : ak;
  const float* arow = adapter + l * 4096;
  const float* wrow = w + (((size_t)col) << 12);
  float sum = 0.f;
#pragma unroll
  for (int i = 0; i < 8; i++) {
    int e = i * 512 + lane * 8;
    float4 a0 = *(const float4*)(arow + e);
    float4 a1 = *(const float4*)(arow + e + 4);
    float4 w0 = *(const float4*)(wrow + e);
    float4 w1 = *(const float4*)(wrow + e + 4);
    sum += a0.x * w0.x + a0.y * w0.y + a0.z * w0.z + a0.w * w0.w
         + a1.x * w1.x + a1.y * w1.y + a1.z * w1.z + a1.w * w1.w;
  }
#pragma unroll
  for (int off = 1; off < 64; off <<= 1) sum += __shfl_xor(sum, off, 64);
  if (lane == 0) o[rem] = f2b(sum);
}

// ---------------------------------------------------------------------------
// Causal flash attention; blockIdx.z = batch. Block = one h x 128 q-rows.
// All LDS tiles XOR-swizzled at 16B-chunk granularity: LDS[row][ch] holds
// global chunk (ch ^ (row&7)).  gload_lds dest stays LINEAR; the global
// SOURCE address carries the swizzle (rule #21).  Reads apply the same XOR.
// ---------------------------------------------------------------------------
__global__ __launch_bounds__(256, 2) void flash_attn(const u16* __restrict__ Q,
    const u16* __restrict__ K, const u16* __restrict__ V, u16* __restrict__ O)
{
  Q += (size_t)blockIdx.z * TNB;
  K += (size_t)blockIdx.z * TNB;
  V += (size_t)blockIdx.z * TNB;
  O += (size_t)blockIdx.z * TNB;
  __shared__ __align__(16) u16 sm[24576];        // 48KB
  u16* Ks = sm;                                  // [64 key][128 d]  swz
  u16* Vs = sm + 8192;                           // [128 d][64 key]  swz
  u16* Ps = sm + 16384;                          // per-wave [32 q][64 key] swz
  const int tid  = threadIdx.x;
  const int wave = tid >> 6, lane = tid & 63;
  const int quad = lane >> 4, l16 = lane & 15;
  const int qt = blockIdx.x;
  const int h  = blockIdx.y;
  const int q0 = qt * 128;
  const size_t qkBase = (size_t)h * 128;
  const size_t vBase  = ((size_t)(h * 128)) << 11;

  // stage Q tile 128x128 into sm[0..16384), swizzled source
#pragma unroll
  for (int i = 0; i < 8; i++) {
    int c = tid + i * 256;
    int row = c >> 4;
    int cb  = ((c & 15) ^ (row & 7)) << 3;
    gload16(Q + qkBase + (((size_t)(q0 + row)) << 12) + cb, sm + c * 8);
  }
  __syncthreads();
  short8 qa[2][4];                               // A-frags: 2 m-tiles x 4 d-steps
#pragma unroll
  for (int mt = 0; mt < 2; mt++)
#pragma unroll
    for (int ks = 0; ks < 4; ks++) {
      int qr = wave * 32 + mt * 16 + l16;
      qa[mt][ks] = *(const short8*)(sm + qr * 128 + (((ks * 4 + quad) ^ (qr & 7)) << 3));
    }

  f32x4 acc_o[2][8];
#pragma unroll
  for (int mt = 0; mt < 2; mt++)
#pragma unroll
    for (int n = 0; n < 8; n++) acc_o[mt][n] = (f32x4)0.0f;
  float m_st[2][4], l_st[2][4];
#pragma unroll
  for (int mt = 0; mt < 2; mt++)
#pragma unroll
    for (int r = 0; r < 4; r++) { m_st[mt][r] = NEGI; l_st[mt][r] = 0.f; }

  const int qw0 = q0 + wave * 32;
  const int ntiles = 2 * (qt + 1);
  for (int t = 0; t < ntiles; t++) {
    const int kv0 = t * 64;
    __syncthreads();                             // prev tile LDS reads done
#pragma unroll
    for (int i = 0; i < 4; i++) {
      int c = tid + i * 256;
      int krow = c >> 4;
      int kcb  = ((c & 15) ^ (krow & 7)) << 3;
      gload16(K + qkBase + (((size_t)(kv0 + krow)) << 12) + kcb, Ks + c * 8);
      int vrow = c >> 3;
      int vcb  = ((c & 7) ^ (vrow & 7)) << 3;
      gload16(V + vBase + (((size_t)vrow) << 11) + kv0 + vcb, Vs + c * 8);
    }
    __syncthreads();                             // staging visible

    if (kv0 <= qw0 + 31) {                       // wave-uniform causal skip
      f32x4 sc[2][4];
#pragma unroll
      for (int mt = 0; mt < 2; mt++)
#pragma unroll
        for (int nt = 0; nt < 4; nt++) sc[mt][nt] = (f32x4)0.0f;
      __builtin_amdgcn_s_setprio(1);
#pragma unroll
      for (int ks = 0; ks < 4; ks++) {
        short8 kb[4];
#pragma unroll
        for (int nt = 0; nt < 4; nt++) {
          int kr = nt * 16 + l16;
          kb[nt] = *(const short8*)(Ks + kr * 128 + (((ks * 4 + quad) ^ (kr & 7)) << 3));
        }
#pragma unroll
        for (int mt = 0; mt < 2; mt++)
#pragma unroll
          for (int nt = 0; nt < 4; nt++)
            sc[mt][nt] = __builtin_amdgcn_mfma_f32_16x16x32_bf16(qa[mt][ks], kb[nt], sc[mt][nt], 0, 0, 0);
      }
      __builtin_amdgcn_s_setprio(0);
      // scale + causal mask
#pragma unroll
      for (int mt = 0; mt < 2; mt++)
#pragma unroll
        for (int nt = 0; nt < 4; nt++)
#pragma unroll
          for (int r = 0; r < 4; r++) {
            int qrow = qw0 + mt * 16 + quad * 4 + r;
            int key  = kv0 + nt * 16 + l16;
            float s = sc[mt][nt][r] * SCALE;
            sc[mt][nt][r] = (key > qrow) ? NEGI : s;
          }
      // online softmax (row = quad*4+r; 16 lanes of the quad share a row)
      float alpha[2][4];
#pragma unroll
      for (int mt = 0; mt < 2; mt++)
#pragma unroll
        for (int r = 0; r < 4; r++) {
          float mx = fmaxf(fmaxf(sc[mt][0][r], sc[mt][1][r]), fmaxf(sc[mt][2][r], sc[mt][3][r]));
          mx = fmaxf(mx, __shfl_xor(mx, 1, 64));
          mx = fmaxf(mx, __shfl_xor(mx, 2, 64));
          mx = fmaxf(mx, __shfl_xor(mx, 4, 64));
          mx = fmaxf(mx, __shfl_xor(mx, 8, 64));
          float mnew = fmaxf(m_st[mt][r], mx);
          float al = __builtin_amdgcn_exp2f((m_st[mt][r] - mnew) * L2E);
          float rs = 0.f;
#pragma unroll
          for (int nt = 0; nt < 4; nt++) {
            float p = __builtin_amdgcn_exp2f((sc[mt][nt][r] - mnew) * L2E);
            sc[mt][nt][r] = p;
            rs += p;
          }
          rs += __shfl_xor(rs, 1, 64);
          rs += __shfl_xor(rs, 2, 64);
          rs += __shfl_xor(rs, 4, 64);
          rs += __shfl_xor(rs, 8, 64);
          l_st[mt][r] = l_st[mt][r] * al + rs;
          m_st[mt][r] = mnew;
          alpha[mt][r] = al;
        }
#pragma unroll
      for (int mt = 0; mt < 2; mt++)
#pragma unroll
        for (int n = 0; n < 8; n++)
#pragma unroll
          for (int r = 0; r < 4; r++) acc_o[mt][n][r] *= alpha[mt][r];
      // P: C-layout -> A-layout via per-wave LDS (chunk-swizzled both sides)
      u16* Pw = Ps + wave * 2048;
#pragma unroll
      for (int mt = 0; mt < 2; mt++)
#pragma unroll
        for (int nt = 0; nt < 4; nt++)
#pragma unroll
          for (int r = 0; r < 4; r++) {
            int prow = mt * 16 + quad * 4 + r;
            int pcol = nt * 16 + l16;
            Pw[prow * 64 + (((pcol >> 3) ^ (prow & 7)) << 3) + (pcol & 7)] = f2b(sc[mt][nt][r]);
          }
      // PV
      __builtin_amdgcn_s_setprio(1);
#pragma unroll
      for (int ks2 = 0; ks2 < 2; ks2++) {
        short8 pa[2];
#pragma unroll
        for (int mt = 0; mt < 2; mt++) {
          int pr = mt * 16 + l16;
          pa[mt] = *(const short8*)(Pw + pr * 64 + (((ks2 * 4 + quad) ^ (pr & 7)) << 3));
        }
#pragma unroll
        for (int n = 0; n < 8; n++) {
          int vr = n * 16 + l16;
          short8 vb = *(const short8*)(Vs + vr * 64 + (((ks2 * 4 + quad) ^ (vr & 7)) << 3));
#pragma unroll
          for (int mt = 0; mt < 2; mt++)
            acc_o[mt][n] = __builtin_amdgcn_mfma_f32_16x16x32_bf16(pa[mt], vb, acc_o[mt][n], 0, 0, 0);
        }
      }
      __builtin_amdgcn_s_setprio(0);
    }
  }
  // epilogue: O[q, h*128+d] = acc / l  (bf16)
#pragma unroll
  for (int mt = 0; mt < 2; mt++)
#pragma unroll
    for (int r = 0; r < 4; r++) {
      float inv = 1.0f / l_st[mt][r];
      int qrow = qw0 + mt * 16 + quad * 4 + r;
#pragma unroll
      for (int n = 0; n < 8; n++) {
        int d = n * 16 + l16;
        O[qkBase + (((size_t)qrow) << 12) + d] = f2b(acc_o[mt][n][r] * inv);
      }
    }
}

// ---------------------------------------------------------------------------
// Adapter attention (full batch): AO += tanh(gate[h]) * softmax(q.a_k/sqrt(d)) a_v
// ---------------------------------------------------------------------------
__global__ __launch_bounds__(256) void adapter_attn(const u16* __restrict__ Q,
    const u16* __restrict__ ak, const u16* __restrict__ av,
    const float* __restrict__ gate, u16* __restrict__ AO)
{
  int gid  = blockIdx.x * 4 + (threadIdx.x >> 6);   // 0..131071 = row*32+h
  int lane = threadIdx.x & 63;
  int row = gid >> 5, h = gid & 31;
  float g = tanhf(gate[h]);
  const u16* qp = Q + (((size_t)row) << 12) + h * 128 + lane * 2;
  float qa = b2f(qp[0]), qb = b2f(qp[1]);
  float p[10];
#pragma unroll
  for (int l = 0; l < 10; l++) {
    const u16* kp = ak + l * 4096 + h * 128 + lane * 2;
    p[l] = qa * b2f(kp[0]) + qb * b2f(kp[1]);
  }
#pragma unroll
  for (int l = 0; l < 10; l++)
#pragma unroll
    for (int off = 1; off < 64; off <<= 1) p[l] += __shfl_xor(p[l], off, 64);
  float m = NEGI;
#pragma unroll
  for (int l = 0; l < 10; l++) { p[l] *= SCALE; m = fmaxf(m, p[l]); }
  float sum = 0.f;
#pragma unroll
  for (int l = 0; l < 10; l++) { p[l] = __builtin_amdgcn_exp2f((p[l] - m) * L2E); sum += p[l]; }
  float gi = g / sum;
  float a0 = 0.f, a1 = 0.f;
#pragma unroll
  for (int l = 0; l < 10; l++) {
    const u16* vp = av + l * 4096 + h * 128 + lane * 2;
    a0 += p[l] * b2f(vp[0]);
    a1 += p[l] * b2f(vp[1]);
  }
  u16* op = AO + (((size_t)row) << 12) + h * 128 + lane * 2;
  op[0] = f2b(b2f(op[0]) + gi * a0);
  op[1] = f2b(b2f(op[1]) + gi * a1);
}

// ---------------------------------------------------------------------------
extern "C" void kernel_launch(void* const* d_in, const int* in_sizes, int n_in,
                              void* d_out, int out_size, void* d_ws, size_t ws_size,
                              hipStream_t stream) {
  (void)in_sizes; (void)n_in; (void)out_size; (void)ws_size;
  const float* x       = (const float*)d_in[0];
  const float* wq      = (const float*)d_in[1];
  const float* wk      = (const float*)d_in[2];
  const float* wv      = (const float*)d_in[3];
  const float* wo      = (const float*)d_in[4];
  const float* gate    = (const float*)d_in[5];
  const float* adapter = (const float*)d_in[6];
  const float* fc      = (const float*)d_in[7];
  const float* fs      = (const float*)d_in[8];
  float* out = (float*)d_out;

  // ws layout (bf16): wb | xb (aliased by AOf) | Qf | Kf | Vtf | ak | av
  u16* wb  = (u16*)d_ws;         // current weight, converted bf16 [4096][4096]
  u16* xb  = wb + WN;            // x bf16 [4096][4096] (both batches)
  u16* Qf  = xb + WN;
  u16* Kf  = Qf + WN;
  u16* Vtf = Kf + WN;            // per-b [4096 cols][2048 s], 2 batches
  u16* AOf = xb;                 // alias: x dead after V GEMM
  u16* ak  = Vtf + WN;           // [10][4096]
  u16* av  = ak + 40960;

  adapter_kv<<<20480, 256, 0, stream>>>(adapter, wk, wv, ak, av);
  cvt_bf16<<<8192, 256, 0, stream>>>(x, xb);

  cvt_bf16<<<8192, 256, 0, stream>>>(wq, wb);
  gemm_nt<<<dim3(32, 32), 256, 0, stream>>>(xb, wb, Qf, 0);
  cvt_bf16<<<8192, 256, 0, stream>>>(wk, wb);
  gemm_nt<<<dim3(32, 32), 256, 0, stream>>>(xb, wb, Kf, 0);
  cvt_bf16<<<8192, 256, 0, stream>>>(wv, wb);
  // V: swap operands so Vt[e][s] writes are coalesced (row=e, col=s)
  gemm_nt<<<dim3(32, 32), 256, 0, stream>>>(wb, xb, Vtf, 1);

  rope_kernel<<<16384, 256, 0, stream>>>(Qf, Kf, fc, fs);
  flash_attn<<<dim3(16, 32, 2), 256, 0, stream>>>(Qf, Kf, Vtf, AOf);
  adapter_attn<<<32768, 256, 0, stream>>>(Qf, ak, av, gate, AOf);

  cvt_bf16<<<8192, 256, 0, stream>>>(wo, wb);
  gemm_nt<<<dim3(32, 32), 256, 0, stream>>>(AOf, wb, out, 2);
}

// Round 3
// 1487.624 us; speedup vs baseline: 1.9498x; 1.0836x over previous
//
#include <hip/hip_runtime.h>

typedef unsigned short u16;
typedef __attribute__((ext_vector_type(8))) short short8;
typedef __attribute__((ext_vector_type(4))) float f32x4;

#define L2E   1.44269504088896340736f
#define SCALE 0.08838834764831845f   // 1/sqrt(128)
#define NEGI  -1e30f
#define WN    ((size_t)4096 * 4096)  // one full [4096][4096] tensor, elems
#define TNB   ((size_t)2048 * 4096)  // one per-b tensor, elems

__device__ __forceinline__ float b2f(u16 u) {
  union { float f; unsigned int i; } v; v.i = ((unsigned int)u) << 16; return v.f;
}
__device__ __forceinline__ u16 f2b(float f) {
  union { float f; unsigned int i; } v; v.f = f;
  unsigned int r = v.i + 0x7fffu + ((v.i >> 16) & 1u);   // RNE
  return (u16)(r >> 16);
}
// async global->LDS, 16B per lane; LDS dest must be wave-uniform base + lane*16
__device__ __forceinline__ void gload16(const u16* g, u16* l) {
  __builtin_amdgcn_global_load_lds((const __attribute__((address_space(1))) void*)g,
                                   (__attribute__((address_space(3))) void*)l, 16, 0, 0);
}
// load 8 fp32, round to 8 bf16
__device__ __forceinline__ short8 ld8_f32_to_bf16(const float* p) {
  float4 a = *(const float4*)p;
  float4 b = *(const float4*)(p + 4);
  short8 pk;
  pk[0] = (short)f2b(a.x); pk[1] = (short)f2b(a.y);
  pk[2] = (short)f2b(a.z); pk[3] = (short)f2b(a.w);
  pk[4] = (short)f2b(b.x); pk[5] = (short)f2b(b.y);
  pk[6] = (short)f2b(b.z); pk[7] = (short)f2b(b.w);
  return pk;
}

// ---------------------------------------------------------------------------
// Streaming fp32 -> bf16 convert, 8 elems/thread.
// ---------------------------------------------------------------------------
__global__ __launch_bounds__(256) void cvt_bf16(const float* __restrict__ src,
                                                u16* __restrict__ dst)
{
  size_t e = ((size_t)blockIdx.x * 256 + threadIdx.x) * 8;
  *(short8*)(dst + e) = ld8_f32_to_bf16(src + e);
}

// ---------------------------------------------------------------------------
// Pure-bf16 NT GEMM (m97 structure): C[m,n] = sum_k A[m,k]*B[n,k].
// M=N=K=4096, both operands via global_load_lds.
// mode 0: C bf16 [4096][4096].
// mode 1: batch-split transpose store: C[(col>>11)*TNB + row*2048 + (col&2047)]
//         (used with A=weight rows=e, B=x rows=s -> coalesced Vt writes).
// mode 2: C fp32 [4096][4096].
// ---------------------------------------------------------------------------
__global__ __launch_bounds__(256, 2) void gemm_nt(const u16* __restrict__ A,
    const u16* __restrict__ B, void* __restrict__ Cv, int mode)
{
  __shared__ __align__(16) u16 As[128 * 64];
  __shared__ __align__(16) u16 Bs[128 * 64];
  const int tid  = threadIdx.x;
  const int wave = tid >> 6, lane = tid & 63;
  const int quad = lane >> 4, l16 = lane & 15;
  const int bm = blockIdx.y * 128, bn = blockIdx.x * 128;
  const int wm = (wave >> 1) * 64, wn = (wave & 1) * 64;

  f32x4 acc[4][4];
#pragma unroll
  for (int i = 0; i < 4; i++)
#pragma unroll
    for (int j = 0; j < 4; j++) acc[i][j] = (f32x4)0.0f;

  for (int k0 = 0; k0 < 4096; k0 += 64) {
    __syncthreads();
#pragma unroll
    for (int i = 0; i < 4; i++) {
      int c = tid + i * 256;
      int row = c >> 3, cb = (c & 7) << 3;
      gload16(A + (((size_t)(bm + row)) << 12) + k0 + cb, As + c * 8);
      gload16(B + (((size_t)(bn + row)) << 12) + k0 + cb, Bs + c * 8);
    }
    __syncthreads();
#pragma unroll
    for (int ks = 0; ks < 2; ks++) {
      short8 af[4], bf[4];
#pragma unroll
      for (int t = 0; t < 4; t++) {
        af[t] = *(const short8*)(As + (wm + t * 16 + l16) * 64 + ks * 32 + quad * 8);
        bf[t] = *(const short8*)(Bs + (wn + t * 16 + l16) * 64 + ks * 32 + quad * 8);
      }
#pragma unroll
      for (int mt = 0; mt < 4; mt++)
#pragma unroll
        for (int nt = 0; nt < 4; nt++)
          acc[mt][nt] = __builtin_amdgcn_mfma_f32_16x16x32_bf16(af[mt], bf[nt], acc[mt][nt], 0, 0, 0);
    }
  }
  // epilogue: C/D layout col=lane&15, row=quad*4+reg
#pragma unroll
  for (int mt = 0; mt < 4; mt++)
#pragma unroll
    for (int nt = 0; nt < 4; nt++)
#pragma unroll
      for (int r = 0; r < 4; r++) {
        int row = bm + wm + mt * 16 + quad * 4 + r;
        int col = bn + wn + nt * 16 + l16;
        float v = acc[mt][nt][r];
        if (mode == 2) {
          ((float*)Cv)[(((size_t)row) << 12) + col] = v;
        } else if (mode == 1) {
          ((u16*)Cv)[((size_t)(col >> 11)) * TNB + (((size_t)row) << 11) + (col & 2047)] = f2b(v);
        } else {
          ((u16*)Cv)[(((size_t)row) << 12) + col] = f2b(v);
        }
      }
}

// ---------------------------------------------------------------------------
// RoPE in-place on full-batch Q and K (4096 rows x 4096, bf16). s = row&2047.
// ---------------------------------------------------------------------------
__global__ __launch_bounds__(256) void rope_kernel(u16* __restrict__ Q, u16* __restrict__ K,
    const float* __restrict__ fc, const float* __restrict__ fs)
{
  int gid = blockIdx.x * 256 + threadIdx.x;     // 2 tensors * 4096 rows * 512 groups
  int tsel = gid >> 21;
  int r = gid & 2097151;
  int row = r >> 9, gp = r & 511;
  int s = row & 2047;
  int e0 = gp * 8;
  int i0 = (e0 >> 1) & 63;
  u16* p = (tsel ? K : Q) + (((size_t)row) << 12) + e0;
  short8 v = *(const short8*)p;
  float4 c4 = *(const float4*)(fc + s * 64 + i0);
  float4 s4 = *(const float4*)(fs + s * 64 + i0);
  float cc[4] = {c4.x, c4.y, c4.z, c4.w};
  float ss[4] = {s4.x, s4.y, s4.z, s4.w};
  short8 w;
#pragma unroll
  for (int j = 0; j < 4; j++) {
    float a  = b2f((u16)v[2 * j]);
    float bb = b2f((u16)v[2 * j + 1]);
    w[2 * j]     = (short)f2b(a * cc[j] - bb * ss[j]);
    w[2 * j + 1] = (short)f2b(a * ss[j] + bb * cc[j]);
  }
  *(short8*)p = w;
}

// ---------------------------------------------------------------------------
// Adapter K/V projection: one wave per output element, shuffle-reduce.
// ---------------------------------------------------------------------------
__global__ __launch_bounds__(256) void adapter_kv(const float* __restrict__ adapter,
    const float* __restrict__ wk, const float* __restrict__ wv,
    u16* __restrict__ ak, u16* __restrict__ av)
{
  int gid  = blockIdx.x * 4 + (threadIdx.x >> 6);   // 0..81919
  int lane = threadIdx.x & 63;
  int which = (gid >= 40960) ? 1 : 0;
  int rem = gid - which * 40960;
  int l = rem >> 12, col = rem & 4095;
  const float* w = which ? wv : wk;
  u16* o = which ? av : ak;
  const float* arow = adapter + l * 4096;
  const float* wrow = w + (((size_t)col) << 12);
  float sum = 0.f;
#pragma unroll
  for (int i = 0; i < 8; i++) {
    int e = i * 512 + lane * 8;
    float4 a0 = *(const float4*)(arow + e);
    float4 a1 = *(const float4*)(arow + e + 4);
    float4 w0 = *(const float4*)(wrow + e);
    float4 w1 = *(const float4*)(wrow + e + 4);
    sum += a0.x * w0.x + a0.y * w0.y + a0.z * w0.z + a0.w * w0.w
         + a1.x * w1.x + a1.y * w1.y + a1.z * w1.z + a1.w * w1.w;
  }
#pragma unroll
  for (int off = 1; off < 64; off <<= 1) sum += __shfl_xor(sum, off, 64);
  if (lane == 0) o[rem] = f2b(sum);
}

// ---------------------------------------------------------------------------
// Causal flash attention. Grid (h=32, b=2, z=16), qt = 15 - blockIdx.z so the
// heaviest (32-tile) blocks dispatch first (causal load-balance / tail-pack).
// K/V double-buffered in LDS; next tile's global_load_lds issued BEFORE the
// current tile's compute (T3 minimum-2-phase: stage || compute, one barrier
// per tile -- __syncthreads' vmcnt(0)+barrier ends the phase).
// LDS 80KB: buf0 [K 16K | V 16K] buf1 [K 16K | V 16K] P 16K. 2 blocks/CU.
// All tiles XOR-swizzled at 16B-chunk granularity (pre-swizzled global src,
// linear gload_lds dest, XOR on read -- rule #21).
// ---------------------------------------------------------------------------
__global__ __launch_bounds__(256, 2) void flash_attn(const u16* __restrict__ Q,
    const u16* __restrict__ K, const u16* __restrict__ V, u16* __restrict__ O)
{
  Q += (size_t)blockIdx.y * TNB;
  K += (size_t)blockIdx.y * TNB;
  V += (size_t)blockIdx.y * TNB;
  O += (size_t)blockIdx.y * TNB;
  __shared__ __align__(16) u16 sm[40960];        // 80KB
  u16* Ps = sm + 32768;                          // per-wave [32 q][64 key] swz
  const int tid  = threadIdx.x;
  const int wave = tid >> 6, lane = tid & 63;
  const int quad = lane >> 4, l16 = lane & 15;
  const int qt = 15 - blockIdx.z;                // heavy blocks first
  const int h  = blockIdx.x;
  const int q0 = qt * 128;
  const size_t qkBase = (size_t)h * 128;
  const size_t vBase  = ((size_t)(h * 128)) << 11;

  // prologue: stage Q (into buf1 region) and KV tile 0 (into buf0) together
  u16* Qs = sm + 16384;
#pragma unroll
  for (int i = 0; i < 8; i++) {
    int c = tid + i * 256;
    int row = c >> 4;
    int cb  = ((c & 15) ^ (row & 7)) << 3;
    gload16(Q + qkBase + (((size_t)(q0 + row)) << 12) + cb, Qs + c * 8);
  }
#pragma unroll
  for (int i = 0; i < 4; i++) {
    int c = tid + i * 256;
    int krow = c >> 4;
    int kcb  = ((c & 15) ^ (krow & 7)) << 3;
    gload16(K + qkBase + (((size_t)krow) << 12) + kcb, sm + c * 8);
    int vrow = c >> 3;
    int vcb  = ((c & 7) ^ (vrow & 7)) << 3;
    gload16(V + vBase + (((size_t)vrow) << 11) + vcb, sm + 8192 + c * 8);
  }
  __syncthreads();                               // Q + tile0 resident
  short8 qa[2][4];                               // A-frags: 2 m-tiles x 4 d-steps
#pragma unroll
  for (int mt = 0; mt < 2; mt++)
#pragma unroll
    for (int ks = 0; ks < 4; ks++) {
      int qr = wave * 32 + mt * 16 + l16;
      qa[mt][ks] = *(const short8*)(Qs + qr * 128 + (((ks * 4 + quad) ^ (qr & 7)) << 3));
    }
  __syncthreads();                               // Q reads done; buf1 reusable

  f32x4 acc_o[2][8];
#pragma unroll
  for (int mt = 0; mt < 2; mt++)
#pragma unroll
    for (int n = 0; n < 8; n++) acc_o[mt][n] = (f32x4)0.0f;
  float m_st[2][4], l_st[2][4];
#pragma unroll
  for (int mt = 0; mt < 2; mt++)
#pragma unroll
    for (int r = 0; r < 4; r++) { m_st[mt][r] = NEGI; l_st[mt][r] = 0.f; }

  const int qw0 = q0 + wave * 32;
  const int ntiles = 2 * (qt + 1);
  for (int t = 0; t < ntiles; t++) {
    const int kv0 = t * 64;
    u16* Kc = sm + (t & 1) * 16384;
    u16* Vc = Kc + 8192;
    // issue next tile's staging BEFORE compute (latency hides under MFMA+VALU)
    if (t + 1 < ntiles) {
      const int nk = kv0 + 64;
      u16* Kn = sm + ((t + 1) & 1) * 16384;
      u16* Vn = Kn + 8192;
#pragma unroll
      for (int i = 0; i < 4; i++) {
        int c = tid + i * 256;
        int krow = c >> 4;
        int kcb  = ((c & 15) ^ (krow & 7)) << 3;
        gload16(K + qkBase + (((size_t)(nk + krow)) << 12) + kcb, Kn + c * 8);
        int vrow = c >> 3;
        int vcb  = ((c & 7) ^ (vrow & 7)) << 3;
        gload16(V + vBase + (((size_t)vrow) << 11) + nk + vcb, Vn + c * 8);
      }
    }

    if (kv0 <= qw0 + 31) {                       // wave-uniform causal skip
      f32x4 sc[2][4];
#pragma unroll
      for (int mt = 0; mt < 2; mt++)
#pragma unroll
        for (int nt = 0; nt < 4; nt++) sc[mt][nt] = (f32x4)0.0f;
      __builtin_amdgcn_s_setprio(1);
#pragma unroll
      for (int ks = 0; ks < 4; ks++) {
        short8 kb[4];
#pragma unroll
        for (int nt = 0; nt < 4; nt++) {
          int kr = nt * 16 + l16;
          kb[nt] = *(const short8*)(Kc + kr * 128 + (((ks * 4 + quad) ^ (kr & 7)) << 3));
        }
#pragma unroll
        for (int mt = 0; mt < 2; mt++)
#pragma unroll
          for (int nt = 0; nt < 4; nt++)
            sc[mt][nt] = __builtin_amdgcn_mfma_f32_16x16x32_bf16(qa[mt][ks], kb[nt], sc[mt][nt], 0, 0, 0);
      }
      __builtin_amdgcn_s_setprio(0);
      // scale + causal mask
#pragma unroll
      for (int mt = 0; mt < 2; mt++)
#pragma unroll
        for (int nt = 0; nt < 4; nt++)
#pragma unroll
          for (int r = 0; r < 4; r++) {
            int qrow = qw0 + mt * 16 + quad * 4 + r;
            int key  = kv0 + nt * 16 + l16;
            float s = sc[mt][nt][r] * SCALE;
            sc[mt][nt][r] = (key > qrow) ? NEGI : s;
          }
      // online softmax (row = quad*4+r; 16 lanes of the quad share a row)
      float alpha[2][4];
#pragma unroll
      for (int mt = 0; mt < 2; mt++)
#pragma unroll
        for (int r = 0; r < 4; r++) {
          float mx = fmaxf(fmaxf(sc[mt][0][r], sc[mt][1][r]), fmaxf(sc[mt][2][r], sc[mt][3][r]));
          mx = fmaxf(mx, __shfl_xor(mx, 1, 64));
          mx = fmaxf(mx, __shfl_xor(mx, 2, 64));
          mx = fmaxf(mx, __shfl_xor(mx, 4, 64));
          mx = fmaxf(mx, __shfl_xor(mx, 8, 64));
          float mnew = fmaxf(m_st[mt][r], mx);
          float al = __builtin_amdgcn_exp2f((m_st[mt][r] - mnew) * L2E);
          float rs = 0.f;
#pragma unroll
          for (int nt = 0; nt < 4; nt++) {
            float p = __builtin_amdgcn_exp2f((sc[mt][nt][r] - mnew) * L2E);
            sc[mt][nt][r] = p;
            rs += p;
          }
          rs += __shfl_xor(rs, 1, 64);
          rs += __shfl_xor(rs, 2, 64);
          rs += __shfl_xor(rs, 4, 64);
          rs += __shfl_xor(rs, 8, 64);
          l_st[mt][r] = l_st[mt][r] * al + rs;
          m_st[mt][r] = mnew;
          alpha[mt][r] = al;
        }
#pragma unroll
      for (int mt = 0; mt < 2; mt++)
#pragma unroll
        for (int n = 0; n < 8; n++)
#pragma unroll
          for (int r = 0; r < 4; r++) acc_o[mt][n][r] *= alpha[mt][r];
      // P: C-layout -> A-layout via per-wave LDS (chunk-swizzled both sides)
      u16* Pw = Ps + wave * 2048;
#pragma unroll
      for (int mt = 0; mt < 2; mt++)
#pragma unroll
        for (int nt = 0; nt < 4; nt++)
#pragma unroll
          for (int r = 0; r < 4; r++) {
            int prow = mt * 16 + quad * 4 + r;
            int pcol = nt * 16 + l16;
            Pw[prow * 64 + (((pcol >> 3) ^ (prow & 7)) << 3) + (pcol & 7)] = f2b(sc[mt][nt][r]);
          }
      // PV
      __builtin_amdgcn_s_setprio(1);
#pragma unroll
      for (int ks2 = 0; ks2 < 2; ks2++) {
        short8 pa[2];
#pragma unroll
        for (int mt = 0; mt < 2; mt++) {
          int pr = mt * 16 + l16;
          pa[mt] = *(const short8*)(Pw + pr * 64 + (((ks2 * 4 + quad) ^ (pr & 7)) << 3));
        }
#pragma unroll
        for (int n = 0; n < 8; n++) {
          int vr = n * 16 + l16;
          short8 vb = *(const short8*)(Vc + vr * 64 + (((ks2 * 4 + quad) ^ (vr & 7)) << 3));
#pragma unroll
          for (int mt = 0; mt < 2; mt++)
            acc_o[mt][n] = __builtin_amdgcn_mfma_f32_16x16x32_bf16(pa[mt], vb, acc_o[mt][n], 0, 0, 0);
        }
      }
      __builtin_amdgcn_s_setprio(0);
    }
    __syncthreads();   // = vmcnt(0)+barrier: next tile staged, compute drained
  }
  // epilogue: O[q, h*128+d] = acc / l  (bf16)
#pragma unroll
  for (int mt = 0; mt < 2; mt++)
#pragma unroll
    for (int r = 0; r < 4; r++) {
      float inv = 1.0f / l_st[mt][r];
      int qrow = qw0 + mt * 16 + quad * 4 + r;
#pragma unroll
      for (int n = 0; n < 8; n++) {
        int d = n * 16 + l16;
        O[qkBase + (((size_t)qrow) << 12) + d] = f2b(acc_o[mt][n][r] * inv);
      }
    }
}

// ---------------------------------------------------------------------------
// Adapter attention (full batch): AO += tanh(gate[h]) * softmax(q.a_k/sqrt(d)) a_v
// ---------------------------------------------------------------------------
__global__ __launch_bounds__(256) void adapter_attn(const u16* __restrict__ Q,
    const u16* __restrict__ ak, const u16* __restrict__ av,
    const float* __restrict__ gate, u16* __restrict__ AO)
{
  int gid  = blockIdx.x * 4 + (threadIdx.x >> 6);   // 0..131071 = row*32+h
  int lane = threadIdx.x & 63;
  int row = gid >> 5, h = gid & 31;
  float g = tanhf(gate[h]);
  const u16* qp = Q + (((size_t)row) << 12) + h * 128 + lane * 2;
  float qa = b2f(qp[0]), qb = b2f(qp[1]);
  float p[10];
#pragma unroll
  for (int l = 0; l < 10; l++) {
    const u16* kp = ak + l * 4096 + h * 128 + lane * 2;
    p[l] = qa * b2f(kp[0]) + qb * b2f(kp[1]);
  }
#pragma unroll
  for (int l = 0; l < 10; l++)
#pragma unroll
    for (int off = 1; off < 64; off <<= 1) p[l] += __shfl_xor(p[l], off, 64);
  float m = NEGI;
#pragma unroll
  for (int l = 0; l < 10; l++) { p[l] *= SCALE; m = fmaxf(m, p[l]); }
  float sum = 0.f;
#pragma unroll
  for (int l = 0; l < 10; l++) { p[l] = __builtin_amdgcn_exp2f((p[l] - m) * L2E); sum += p[l]; }
  float gi = g / sum;
  float a0 = 0.f, a1 = 0.f;
#pragma unroll
  for (int l = 0; l < 10; l++) {
    const u16* vp = av + l * 4096 + h * 128 + lane * 2;
    a0 += p[l] * b2f(vp[0]);
    a1 += p[l] * b2f(vp[1]);
  }
  u16* op = AO + (((size_t)row) << 12) + h * 128 + lane * 2;
  op[0] = f2b(b2f(op[0]) + gi * a0);
  op[1] = f2b(b2f(op[1]) + gi * a1);
}

// ---------------------------------------------------------------------------
extern "C" void kernel_launch(void* const* d_in, const int* in_sizes, int n_in,
                              void* d_out, int out_size, void* d_ws, size_t ws_size,
                              hipStream_t stream) {
  (void)in_sizes; (void)n_in; (void)out_size; (void)ws_size;
  const float* x       = (const float*)d_in[0];
  const float* wq      = (const float*)d_in[1];
  const float* wk      = (const float*)d_in[2];
  const float* wv      = (const float*)d_in[3];
  const float* wo      = (const float*)d_in[4];
  const float* gate    = (const float*)d_in[5];
  const float* adapter = (const float*)d_in[6];
  const float* fc      = (const float*)d_in[7];
  const float* fs      = (const float*)d_in[8];
  float* out = (float*)d_out;

  // ws layout (bf16): wb | xb (aliased by AOf) | Qf | Kf | Vtf | ak | av
  u16* wb  = (u16*)d_ws;         // current weight, converted bf16 [4096][4096]
  u16* xb  = wb + WN;            // x bf16 [4096][4096] (both batches)
  u16* Qf  = xb + WN;
  u16* Kf  = Qf + WN;
  u16* Vtf = Kf + WN;            // per-b [4096 cols][2048 s], 2 batches
  u16* AOf = xb;                 // alias: x dead after V GEMM
  u16* ak  = Vtf + WN;           // [10][4096]
  u16* av  = ak + 40960;

  adapter_kv<<<20480, 256, 0, stream>>>(adapter, wk, wv, ak, av);
  cvt_bf16<<<8192, 256, 0, stream>>>(x, xb);

  cvt_bf16<<<8192, 256, 0, stream>>>(wq, wb);
  gemm_nt<<<dim3(32, 32), 256, 0, stream>>>(xb, wb, Qf, 0);
  cvt_bf16<<<8192, 256, 0, stream>>>(wk, wb);
  gemm_nt<<<dim3(32, 32), 256, 0, stream>>>(xb, wb, Kf, 0);
  cvt_bf16<<<8192, 256, 0, stream>>>(wv, wb);
  // V: swap operands so Vt[e][s] writes are coalesced (row=e, col=s)
  gemm_nt<<<dim3(32, 32), 256, 0, stream>>>(wb, xb, Vtf, 1);

  rope_kernel<<<16384, 256, 0, stream>>>(Qf, Kf, fc, fs);
  flash_attn<<<dim3(32, 2, 16), 256, 0, stream>>>(Qf, Kf, Vtf, AOf);
  adapter_attn<<<32768, 256, 0, stream>>>(Qf, ak, av, gate, AOf);

  cvt_bf16<<<8192, 256, 0, stream>>>(wo, wb);
  gemm_nt<<<dim3(32, 32), 256, 0, stream>>>(AOf, wb, out, 2);
}

// Round 4
// 1485.627 us; speedup vs baseline: 1.9524x; 1.0013x over previous
//
#include <hip/hip_runtime.h>

typedef unsigned short u16;
typedef __attribute__((ext_vector_type(8))) short short8;
typedef __attribute__((ext_vector_type(4))) float f32x4;

#define L2E   1.44269504088896340736f
#define SCALE 0.08838834764831845f   // 1/sqrt(128)
#define NEGI  -1e30f
#define WN    ((size_t)4096 * 4096)  // one full [4096][4096] tensor, elems
#define TNB   ((size_t)2048 * 4096)  // one per-b tensor, elems

__device__ __forceinline__ float b2f(u16 u) {
  union { float f; unsigned int i; } v; v.i = ((unsigned int)u) << 16; return v.f;
}
__device__ __forceinline__ u16 f2b(float f) {
  union { float f; unsigned int i; } v; v.f = f;
  unsigned int r = v.i + 0x7fffu + ((v.i >> 16) & 1u);   // RNE
  return (u16)(r >> 16);
}
// async global->LDS, 16B per lane; LDS dest must be wave-uniform base + lane*16
__device__ __forceinline__ void gload16(const u16* g, u16* l) {
  __builtin_amdgcn_global_load_lds((const __attribute__((address_space(1))) void*)g,
                                   (__attribute__((address_space(3))) void*)l, 16, 0, 0);
}
// load 8 fp32, round to 8 bf16
__device__ __forceinline__ short8 ld8_f32_to_bf16(const float* p) {
  float4 a = *(const float4*)p;
  float4 b = *(const float4*)(p + 4);
  short8 pk;
  pk[0] = (short)f2b(a.x); pk[1] = (short)f2b(a.y);
  pk[2] = (short)f2b(a.z); pk[3] = (short)f2b(a.w);
  pk[4] = (short)f2b(b.x); pk[5] = (short)f2b(b.y);
  pk[6] = (short)f2b(b.z); pk[7] = (short)f2b(b.w);
  return pk;
}

// ---------------------------------------------------------------------------
// Streaming fp32 -> bf16 convert, 8 elems/thread.
// ---------------------------------------------------------------------------
__global__ __launch_bounds__(256) void cvt_bf16(const float* __restrict__ src,
                                                u16* __restrict__ dst)
{
  size_t e = ((size_t)blockIdx.x * 256 + threadIdx.x) * 8;
  *(short8*)(dst + e) = ld8_f32_to_bf16(src + e);
}

// ---------------------------------------------------------------------------
// Pure-bf16 NT GEMM: C[m,n] = sum_k A[m,k]*B[n,k].  M=N=K=4096.
// Double-buffered LDS, stage-ahead (tile t+1's global_load_lds issued BEFORE
// tile t's compute; the end-of-iter __syncthreads provides vmcnt(0)+barrier).
// Tiles chunk-XOR swizzled at 16B granularity (pre-swizzled global source,
// linear gload_lds dest, XOR on read) -- kills the 16-way ds_read conflict.
// mode 0: C bf16 [4096][4096].
// mode 1: batch-split transpose store: C[(col>>11)*TNB + row*2048 + (col&2047)]
// mode 2: C fp32 [4096][4096].
// ---------------------------------------------------------------------------
__global__ __launch_bounds__(256, 2) void gemm_nt(const u16* __restrict__ A,
    const u16* __restrict__ B, void* __restrict__ Cv, int mode)
{
  __shared__ __align__(16) u16 As[2][128 * 64];
  __shared__ __align__(16) u16 Bs[2][128 * 64];
  const int tid  = threadIdx.x;
  const int wave = tid >> 6, lane = tid & 63;
  const int quad = lane >> 4, l16 = lane & 15;
  const int bm = blockIdx.y * 128, bn = blockIdx.x * 128;
  const int wm = (wave >> 1) * 64, wn = (wave & 1) * 64;

  f32x4 acc[4][4];
#pragma unroll
  for (int i = 0; i < 4; i++)
#pragma unroll
    for (int j = 0; j < 4; j++) acc[i][j] = (f32x4)0.0f;

  // prologue: stage tile 0 into buf0 (swizzled source)
#pragma unroll
  for (int i = 0; i < 4; i++) {
    int c = tid + i * 256;
    int row = c >> 3;
    int cb  = ((c & 7) ^ (row & 7)) << 3;
    gload16(A + (((size_t)(bm + row)) << 12) + cb, As[0] + c * 8);
    gload16(B + (((size_t)(bn + row)) << 12) + cb, Bs[0] + c * 8);
  }
  __syncthreads();                               // tile 0 resident

  for (int t = 0; t < 64; t++) {
    const int bi = t & 1;
    // issue next tile's staging BEFORE compute (hides HBM latency under MFMA)
    if (t < 63) {
      const int k0 = (t + 1) * 64;
#pragma unroll
      for (int i = 0; i < 4; i++) {
        int c = tid + i * 256;
        int row = c >> 3;
        int cb  = ((c & 7) ^ (row & 7)) << 3;
        gload16(A + (((size_t)(bm + row)) << 12) + k0 + cb, As[bi ^ 1] + c * 8);
        gload16(B + (((size_t)(bn + row)) << 12) + k0 + cb, Bs[bi ^ 1] + c * 8);
      }
    }
#pragma unroll
    for (int ks = 0; ks < 2; ks++) {
      short8 af[4], bf[4];
#pragma unroll
      for (int tt = 0; tt < 4; tt++) {
        int ar = wm + tt * 16 + l16;
        int br = wn + tt * 16 + l16;
        af[tt] = *(const short8*)(As[bi] + ar * 64 + (((ks * 4 + quad) ^ (ar & 7)) << 3));
        bf[tt] = *(const short8*)(Bs[bi] + br * 64 + (((ks * 4 + quad) ^ (br & 7)) << 3));
      }
#pragma unroll
      for (int mt = 0; mt < 4; mt++)
#pragma unroll
        for (int nt = 0; nt < 4; nt++)
          acc[mt][nt] = __builtin_amdgcn_mfma_f32_16x16x32_bf16(af[mt], bf[nt], acc[mt][nt], 0, 0, 0);
    }
    __syncthreads();   // vmcnt(0)+barrier: tile t+1 staged, reads of buf bi done
  }
  // epilogue: C/D layout col=lane&15, row=quad*4+reg
#pragma unroll
  for (int mt = 0; mt < 4; mt++)
#pragma unroll
    for (int nt = 0; nt < 4; nt++)
#pragma unroll
      for (int r = 0; r < 4; r++) {
        int row = bm + wm + mt * 16 + quad * 4 + r;
        int col = bn + wn + nt * 16 + l16;
        float v = acc[mt][nt][r];
        if (mode == 2) {
          ((float*)Cv)[(((size_t)row) << 12) + col] = v;
        } else if (mode == 1) {
          ((u16*)Cv)[((size_t)(col >> 11)) * TNB + (((size_t)row) << 11) + (col & 2047)] = f2b(v);
        } else {
          ((u16*)Cv)[(((size_t)row) << 12) + col] = f2b(v);
        }
      }
}

// ---------------------------------------------------------------------------
// RoPE in-place on full-batch Q and K (4096 rows x 4096, bf16). s = row&2047.
// ---------------------------------------------------------------------------
__global__ __launch_bounds__(256) void rope_kernel(u16* __restrict__ Q, u16* __restrict__ K,
    const float* __restrict__ fc, const float* __restrict__ fs)
{
  int gid = blockIdx.x * 256 + threadIdx.x;     // 2 tensors * 4096 rows * 512 groups
  int tsel = gid >> 21;
  int r = gid & 2097151;
  int row = r >> 9, gp = r & 511;
  int s = row & 2047;
  int e0 = gp * 8;
  int i0 = (e0 >> 1) & 63;
  u16* p = (tsel ? K : Q) + (((size_t)row) << 12) + e0;
  short8 v = *(const short8*)p;
  float4 c4 = *(const float4*)(fc + s * 64 + i0);
  float4 s4 = *(const float4*)(fs + s * 64 + i0);
  float cc[4] = {c4.x, c4.y, c4.z, c4.w};
  float ss[4] = {s4.x, s4.y, s4.z, s4.w};
  short8 w;
#pragma unroll
  for (int j = 0; j < 4; j++) {
    float a  = b2f((u16)v[2 * j]);
    float bb = b2f((u16)v[2 * j + 1]);
    w[2 * j]     = (short)f2b(a * cc[j] - bb * ss[j]);
    w[2 * j + 1] = (short)f2b(a * ss[j] + bb * cc[j]);
  }
  *(short8*)p = w;
}

// ---------------------------------------------------------------------------
// Adapter K/V projection: one wave per output element, shuffle-reduce.
// ---------------------------------------------------------------------------
__global__ __launch_bounds__(256) void adapter_kv(const float* __restrict__ adapter,
    const float* __restrict__ wk, const float* __restrict__ wv,
    u16* __restrict__ ak, u16* __restrict__ av)
{
  int gid  = blockIdx.x * 4 + (threadIdx.x >> 6);   // 0..81919
  int lane = threadIdx.x & 63;
  int which = (gid >= 40960) ? 1 : 0;
  int rem = gid - which * 40960;
  int l = rem >> 12, col = rem & 4095;
  const float* w = which ? wv : wk;
  u16* o = which ? av : ak;
  const float* arow = adapter + l * 4096;
  const float* wrow = w + (((size_t)col) << 12);
  float sum = 0.f;
#pragma unroll
  for (int i = 0; i < 8; i++) {
    int e = i * 512 + lane * 8;
    float4 a0 = *(const float4*)(arow + e);
    float4 a1 = *(const float4*)(arow + e + 4);
    float4 w0 = *(const float4*)(wrow + e);
    float4 w1 = *(const float4*)(wrow + e + 4);
    sum += a0.x * w0.x + a0.y * w0.y + a0.z * w0.z + a0.w * w0.w
         + a1.x * w1.x + a1.y * w1.y + a1.z * w1.z + a1.w * w1.w;
  }
#pragma unroll
  for (int off = 1; off < 64; off <<= 1) sum += __shfl_xor(sum, off, 64);
  if (lane == 0) o[rem] = f2b(sum);
}

// ---------------------------------------------------------------------------
// Causal flash attention. Grid (h=32, b=2, z=16), qt = 15 - blockIdx.z so the
// heaviest (32-tile) blocks dispatch first (causal load-balance / tail-pack).
// K/V double-buffered in LDS; next tile's global_load_lds issued BEFORE the
// current tile's compute. LDS 80KB; 2 blocks/CU. Chunk-XOR swizzled tiles.
// ---------------------------------------------------------------------------
__global__ __launch_bounds__(256, 2) void flash_attn(const u16* __restrict__ Q,
    const u16* __restrict__ K, const u16* __restrict__ V, u16* __restrict__ O)
{
  Q += (size_t)blockIdx.y * TNB;
  K += (size_t)blockIdx.y * TNB;
  V += (size_t)blockIdx.y * TNB;
  O += (size_t)blockIdx.y * TNB;
  __shared__ __align__(16) u16 sm[40960];        // 80KB
  u16* Ps = sm + 32768;                          // per-wave [32 q][64 key] swz
  const int tid  = threadIdx.x;
  const int wave = tid >> 6, lane = tid & 63;
  const int quad = lane >> 4, l16 = lane & 15;
  const int qt = 15 - blockIdx.z;                // heavy blocks first
  const int h  = blockIdx.x;
  const int q0 = qt * 128;
  const size_t qkBase = (size_t)h * 128;
  const size_t vBase  = ((size_t)(h * 128)) << 11;

  // prologue: stage Q (into buf1 region) and KV tile 0 (into buf0) together
  u16* Qs = sm + 16384;
#pragma unroll
  for (int i = 0; i < 8; i++) {
    int c = tid + i * 256;
    int row = c >> 4;
    int cb  = ((c & 15) ^ (row & 7)) << 3;
    gload16(Q + qkBase + (((size_t)(q0 + row)) << 12) + cb, Qs + c * 8);
  }
#pragma unroll
  for (int i = 0; i < 4; i++) {
    int c = tid + i * 256;
    int krow = c >> 4;
    int kcb  = ((c & 15) ^ (krow & 7)) << 3;
    gload16(K + qkBase + (((size_t)krow) << 12) + kcb, sm + c * 8);
    int vrow = c >> 3;
    int vcb  = ((c & 7) ^ (vrow & 7)) << 3;
    gload16(V + vBase + (((size_t)vrow) << 11) + vcb, sm + 8192 + c * 8);
  }
  __syncthreads();                               // Q + tile0 resident
  short8 qa[2][4];                               // A-frags: 2 m-tiles x 4 d-steps
#pragma unroll
  for (int mt = 0; mt < 2; mt++)
#pragma unroll
    for (int ks = 0; ks < 4; ks++) {
      int qr = wave * 32 + mt * 16 + l16;
      qa[mt][ks] = *(const short8*)(Qs + qr * 128 + (((ks * 4 + quad) ^ (qr & 7)) << 3));
    }
  __syncthreads();                               // Q reads done; buf1 reusable

  f32x4 acc_o[2][8];
#pragma unroll
  for (int mt = 0; mt < 2; mt++)
#pragma unroll
    for (int n = 0; n < 8; n++) acc_o[mt][n] = (f32x4)0.0f;
  float m_st[2][4], l_st[2][4];
#pragma unroll
  for (int mt = 0; mt < 2; mt++)
#pragma unroll
    for (int r = 0; r < 4; r++) { m_st[mt][r] = NEGI; l_st[mt][r] = 0.f; }

  const int qw0 = q0 + wave * 32;
  const int ntiles = 2 * (qt + 1);
  for (int t = 0; t < ntiles; t++) {
    const int kv0 = t * 64;
    u16* Kc = sm + (t & 1) * 16384;
    u16* Vc = Kc + 8192;
    // issue next tile's staging BEFORE compute (latency hides under MFMA+VALU)
    if (t + 1 < ntiles) {
      const int nk = kv0 + 64;
      u16* Kn = sm + ((t + 1) & 1) * 16384;
      u16* Vn = Kn + 8192;
#pragma unroll
      for (int i = 0; i < 4; i++) {
        int c = tid + i * 256;
        int krow = c >> 4;
        int kcb  = ((c & 15) ^ (krow & 7)) << 3;
        gload16(K + qkBase + (((size_t)(nk + krow)) << 12) + kcb, Kn + c * 8);
        int vrow = c >> 3;
        int vcb  = ((c & 7) ^ (vrow & 7)) << 3;
        gload16(V + vBase + (((size_t)vrow) << 11) + nk + vcb, Vn + c * 8);
      }
    }

    if (kv0 <= qw0 + 31) {                       // wave-uniform causal skip
      f32x4 sc[2][4];
#pragma unroll
      for (int mt = 0; mt < 2; mt++)
#pragma unroll
        for (int nt = 0; nt < 4; nt++) sc[mt][nt] = (f32x4)0.0f;
      __builtin_amdgcn_s_setprio(1);
#pragma unroll
      for (int ks = 0; ks < 4; ks++) {
        short8 kb[4];
#pragma unroll
        for (int nt = 0; nt < 4; nt++) {
          int kr = nt * 16 + l16;
          kb[nt] = *(const short8*)(Kc + kr * 128 + (((ks * 4 + quad) ^ (kr & 7)) << 3));
        }
#pragma unroll
        for (int mt = 0; mt < 2; mt++)
#pragma unroll
          for (int nt = 0; nt < 4; nt++)
            sc[mt][nt] = __builtin_amdgcn_mfma_f32_16x16x32_bf16(qa[mt][ks], kb[nt], sc[mt][nt], 0, 0, 0);
      }
      __builtin_amdgcn_s_setprio(0);
      // scale + causal mask
#pragma unroll
      for (int mt = 0; mt < 2; mt++)
#pragma unroll
        for (int nt = 0; nt < 4; nt++)
#pragma unroll
          for (int r = 0; r < 4; r++) {
            int qrow = qw0 + mt * 16 + quad * 4 + r;
            int key  = kv0 + nt * 16 + l16;
            float s = sc[mt][nt][r] * SCALE;
            sc[mt][nt][r] = (key > qrow) ? NEGI : s;
          }
      // online softmax (row = quad*4+r; 16 lanes of the quad share a row)
      float alpha[2][4];
#pragma unroll
      for (int mt = 0; mt < 2; mt++)
#pragma unroll
        for (int r = 0; r < 4; r++) {
          float mx = fmaxf(fmaxf(sc[mt][0][r], sc[mt][1][r]), fmaxf(sc[mt][2][r], sc[mt][3][r]));
          mx = fmaxf(mx, __shfl_xor(mx, 1, 64));
          mx = fmaxf(mx, __shfl_xor(mx, 2, 64));
          mx = fmaxf(mx, __shfl_xor(mx, 4, 64));
          mx = fmaxf(mx, __shfl_xor(mx, 8, 64));
          float mnew = fmaxf(m_st[mt][r], mx);
          float al = __builtin_amdgcn_exp2f((m_st[mt][r] - mnew) * L2E);
          float rs = 0.f;
#pragma unroll
          for (int nt = 0; nt < 4; nt++) {
            float p = __builtin_amdgcn_exp2f((sc[mt][nt][r] - mnew) * L2E);
            sc[mt][nt][r] = p;
            rs += p;
          }
          rs += __shfl_xor(rs, 1, 64);
          rs += __shfl_xor(rs, 2, 64);
          rs += __shfl_xor(rs, 4, 64);
          rs += __shfl_xor(rs, 8, 64);
          l_st[mt][r] = l_st[mt][r] * al + rs;
          m_st[mt][r] = mnew;
          alpha[mt][r] = al;
        }
#pragma unroll
      for (int mt = 0; mt < 2; mt++)
#pragma unroll
        for (int n = 0; n < 8; n++)
#pragma unroll
          for (int r = 0; r < 4; r++) acc_o[mt][n][r] *= alpha[mt][r];
      // P: C-layout -> A-layout via per-wave LDS (chunk-swizzled both sides)
      u16* Pw = Ps + wave * 2048;
#pragma unroll
      for (int mt = 0; mt < 2; mt++)
#pragma unroll
        for (int nt = 0; nt < 4; nt++)
#pragma unroll
          for (int r = 0; r < 4; r++) {
            int prow = mt * 16 + quad * 4 + r;
            int pcol = nt * 16 + l16;
            Pw[prow * 64 + (((pcol >> 3) ^ (prow & 7)) << 3) + (pcol & 7)] = f2b(sc[mt][nt][r]);
          }
      // PV
      __builtin_amdgcn_s_setprio(1);
#pragma unroll
      for (int ks2 = 0; ks2 < 2; ks2++) {
        short8 pa[2];
#pragma unroll
        for (int mt = 0; mt < 2; mt++) {
          int pr = mt * 16 + l16;
          pa[mt] = *(const short8*)(Pw + pr * 64 + (((ks2 * 4 + quad) ^ (pr & 7)) << 3));
        }
#pragma unroll
        for (int n = 0; n < 8; n++) {
          int vr = n * 16 + l16;
          short8 vb = *(const short8*)(Vc + vr * 64 + (((ks2 * 4 + quad) ^ (vr & 7)) << 3));
#pragma unroll
          for (int mt = 0; mt < 2; mt++)
            acc_o[mt][n] = __builtin_amdgcn_mfma_f32_16x16x32_bf16(pa[mt], vb, acc_o[mt][n], 0, 0, 0);
        }
      }
      __builtin_amdgcn_s_setprio(0);
    }
    __syncthreads();   // = vmcnt(0)+barrier: next tile staged, compute drained
  }
  // epilogue: O[q, h*128+d] = acc / l  (bf16)
#pragma unroll
  for (int mt = 0; mt < 2; mt++)
#pragma unroll
    for (int r = 0; r < 4; r++) {
      float inv = 1.0f / l_st[mt][r];
      int qrow = qw0 + mt * 16 + quad * 4 + r;
#pragma unroll
      for (int n = 0; n < 8; n++) {
        int d = n * 16 + l16;
        O[qkBase + (((size_t)qrow) << 12) + d] = f2b(acc_o[mt][n][r] * inv);
      }
    }
}

// ---------------------------------------------------------------------------
// Adapter attention (full batch): AO += tanh(gate[h]) * softmax(q.a_k/sqrt(d)) a_v
// ---------------------------------------------------------------------------
__global__ __launch_bounds__(256) void adapter_attn(const u16* __restrict__ Q,
    const u16* __restrict__ ak, const u16* __restrict__ av,
    const float* __restrict__ gate, u16* __restrict__ AO)
{
  int gid  = blockIdx.x * 4 + (threadIdx.x >> 6);   // 0..131071 = row*32+h
  int lane = threadIdx.x & 63;
  int row = gid >> 5, h = gid & 31;
  float g = tanhf(gate[h]);
  const u16* qp = Q + (((size_t)row) << 12) + h * 128 + lane * 2;
  float qa = b2f(qp[0]), qb = b2f(qp[1]);
  float p[10];
#pragma unroll
  for (int l = 0; l < 10; l++) {
    const u16* kp = ak + l * 4096 + h * 128 + lane * 2;
    p[l] = qa * b2f(kp[0]) + qb * b2f(kp[1]);
  }
#pragma unroll
  for (int l = 0; l < 10; l++)
#pragma unroll
    for (int off = 1; off < 64; off <<= 1) p[l] += __shfl_xor(p[l], off, 64);
  float m = NEGI;
#pragma unroll
  for (int l = 0; l < 10; l++) { p[l] *= SCALE; m = fmaxf(m, p[l]); }
  float sum = 0.f;
#pragma unroll
  for (int l = 0; l < 10; l++) { p[l] = __builtin_amdgcn_exp2f((p[l] - m) * L2E); sum += p[l]; }
  float gi = g / sum;
  float a0 = 0.f, a1 = 0.f;
#pragma unroll
  for (int l = 0; l < 10; l++) {
    const u16* vp = av + l * 4096 + h * 128 + lane * 2;
    a0 += p[l] * b2f(vp[0]);
    a1 += p[l] * b2f(vp[1]);
  }
  u16* op = AO + (((size_t)row) << 12) + h * 128 + lane * 2;
  op[0] = f2b(b2f(op[0]) + gi * a0);
  op[1] = f2b(b2f(op[1]) + gi * a1);
}

// ---------------------------------------------------------------------------
extern "C" void kernel_launch(void* const* d_in, const int* in_sizes, int n_in,
                              void* d_out, int out_size, void* d_ws, size_t ws_size,
                              hipStream_t stream) {
  (void)in_sizes; (void)n_in; (void)out_size; (void)ws_size;
  const float* x       = (const float*)d_in[0];
  const float* wq      = (const float*)d_in[1];
  const float* wk      = (const float*)d_in[2];
  const float* wv      = (const float*)d_in[3];
  const float* wo      = (const float*)d_in[4];
  const float* gate    = (const float*)d_in[5];
  const float* adapter = (const float*)d_in[6];
  const float* fc      = (const float*)d_in[7];
  const float* fs      = (const float*)d_in[8];
  float* out = (float*)d_out;

  // ws layout (bf16): wb | xb (aliased by AOf) | Qf | Kf | Vtf | ak | av
  u16* wb  = (u16*)d_ws;         // current weight, converted bf16 [4096][4096]
  u16* xb  = wb + WN;            // x bf16 [4096][4096] (both batches)
  u16* Qf  = xb + WN;
  u16* Kf  = Qf + WN;
  u16* Vtf = Kf + WN;            // per-b [4096 cols][2048 s], 2 batches
  u16* AOf = xb;                 // alias: x dead after V GEMM
  u16* ak  = Vtf + WN;           // [10][4096]
  u16* av  = ak + 40960;

  adapter_kv<<<20480, 256, 0, stream>>>(adapter, wk, wv, ak, av);
  cvt_bf16<<<8192, 256, 0, stream>>>(x, xb);

  cvt_bf16<<<8192, 256, 0, stream>>>(wq, wb);
  gemm_nt<<<dim3(32, 32), 256, 0, stream>>>(xb, wb, Qf, 0);
  cvt_bf16<<<8192, 256, 0, stream>>>(wk, wb);
  gemm_nt<<<dim3(32, 32), 256, 0, stream>>>(xb, wb, Kf, 0);
  cvt_bf16<<<8192, 256, 0, stream>>>(wv, wb);
  // V: swap operands so Vt[e][s] writes are coalesced (row=e, col=s)
  gemm_nt<<<dim3(32, 32), 256, 0, stream>>>(wb, xb, Vtf, 1);

  rope_kernel<<<16384, 256, 0, stream>>>(Qf, Kf, fc, fs);
  flash_attn<<<dim3(32, 2, 16), 256, 0, stream>>>(Qf, Kf, Vtf, AOf);
  adapter_attn<<<32768, 256, 0, stream>>>(Qf, ak, av, gate, AOf);

  cvt_bf16<<<8192, 256, 0, stream>>>(wo, wb);
  gemm_nt<<<dim3(32, 32), 256, 0, stream>>>(AOf, wb, out, 2);
}